// Round 8
// baseline (709.441 us; speedup 1.0000x reference)
//
#include <hip/hip_runtime.h>
#include <cstdint>

constexpr int NG = 64;     // graphs
constexpr int H  = 256;    // hidden width

typedef __bf16 bf16x8 __attribute__((ext_vector_type(8)));
typedef float  f32x4  __attribute__((ext_vector_type(4)));

__device__ __forceinline__ uint32_t pk_bf16(float a, float b) {
    uint32_t ua = __builtin_bit_cast(uint32_t, a);
    uint32_t ub = __builtin_bit_cast(uint32_t, b);
    ua += 0x7fffu + ((ua >> 16) & 1u);
    ub += 0x7fffu + ((ub >> 16) & 1u);
    return (ua >> 16) | (ub & 0xffff0000u);
}
__device__ __forceinline__ ushort bf16r(float x) {
    uint32_t u = __builtin_bit_cast(uint32_t, x);
    u += 0x7fffu + ((u >> 16) & 1u);
    return (ushort)(u >> 16);
}
__device__ __forceinline__ float bf2f(ushort h) {
    return __builtin_bit_cast(float, ((uint32_t)h) << 16);
}
__device__ __forceinline__ void bf2acc(uint32_t u, float& a0, float& a1) {
    a0 += __builtin_bit_cast(float, u << 16);
    a1 += __builtin_bit_cast(float, u & 0xffff0000u);
}

// ---------- degree histogram ----------
__global__ void hist_kernel(const int* __restrict__ dst, int* __restrict__ cnt, int E) {
    int e = blockIdx.x * blockDim.x + threadIdx.x;
    if (e < E) atomicAdd(&cnt[dst[e]], 1);
}

// ---------- scanA + dinv ----------
__global__ __launch_bounds__(256) void scanA(const int* __restrict__ cnt, int* __restrict__ bsum,
                                             float* __restrict__ dinv, int n) {
    __shared__ int sh[256];
    int t = threadIdx.x, i = blockIdx.x * 256 + t;
    int v = (i < n) ? cnt[i] : 0;
    if (i < n) dinv[i] = rsqrtf((float)(v + 1));
    sh[t] = v;
    __syncthreads();
    for (int off = 128; off > 0; off >>= 1) {
        if (t < off) sh[t] += sh[t + off];
        __syncthreads();
    }
    if (t == 0) bsum[blockIdx.x] = sh[0];
}

// ---------- scanB + zero sums/gcnt ----------
__global__ __launch_bounds__(256) void scanB(const int* __restrict__ bsum, int* __restrict__ boff,
                                             int* __restrict__ total_out, int nb,
                                             float* __restrict__ sums, int* __restrict__ gcnt) {
    __shared__ int sh[256];
    int t = threadIdx.x;
    for (int i = t; i < NG * H; i += 256) sums[i] = 0.f;
    if (t < NG) gcnt[t] = 0;
    int v = (t < nb) ? bsum[t] : 0;
    sh[t] = v;
    __syncthreads();
    for (int off = 1; off < 256; off <<= 1) {
        int a = (t >= off) ? sh[t - off] : 0;
        __syncthreads();
        sh[t] += a;
        __syncthreads();
    }
    if (t < nb) boff[t] = sh[t] - v;
    if (t == nb - 1) *total_out = sh[t];
}

__global__ __launch_bounds__(256) void scanC(const int* __restrict__ cnt, const int* __restrict__ boff,
                                             int* __restrict__ row_ptr, int* __restrict__ fill, int n) {
    __shared__ int sh[256];
    int t = threadIdx.x, i = blockIdx.x * 256 + t;
    int v = (i < n) ? cnt[i] : 0;
    sh[t] = v;
    __syncthreads();
    for (int off = 1; off < 256; off <<= 1) {
        int a = (t >= off) ? sh[t - off] : 0;
        __syncthreads();
        sh[t] += a;
        __syncthreads();
    }
    if (i < n) {
        int excl = boff[blockIdx.x] + sh[t] - v;
        row_ptr[i] = excl;
        fill[i] = excl;
    }
}

// ---------- fused: wconv (both W) + counting-sort scatter + prescale ----------
// y layout: chunk-major [4][N][32] bf16 (width 128)
constexpr int WCONV_BLOCKS = (128 * 256 + 256 * 256) / 256;   // 384
__global__ void wsp_kernel(const float* __restrict__ w1, ushort* __restrict__ h1, ushort* __restrict__ l1,
                           const float* __restrict__ w2, ushort* __restrict__ h2, ushort* __restrict__ l2,
                           const int* __restrict__ src, const int* __restrict__ dst,
                           int* __restrict__ fill, ushort* __restrict__ ssrc, int E,
                           const float* __restrict__ x, const float* __restrict__ dinv,
                           ushort* __restrict__ y, int N) {
    if (blockIdx.x < WCONV_BLOCKS) {
        int idx = blockIdx.x * 256 + threadIdx.x;
        const float* w; ushort *hi, *lo; int K;
        if (idx < 128 * 256) { w = w1; hi = h1; lo = l1; K = 128; }
        else { idx -= 128 * 256; w = w2; hi = h2; lo = l2; K = 256; }
        int k = idx / 256, n = idx & 255;
        float v = w[idx];
        ushort h = bf16r(v);
        float r = v - bf2f(h);
        hi[n * K + k] = h;
        lo[n * K + k] = bf16r(r);
        return;
    }
    int i = (blockIdx.x - WCONV_BLOCKS) * 256 + threadIdx.x;
    if (i < E) {
        int pos = atomicAdd(&fill[dst[i]], 1);
        ssrc[pos] = (ushort)src[i];
    }
    int np4 = N * 32;   // N*128/4
    if (i < np4) {
        int f = i * 4;
        int node = f >> 7;
        int k = f & 127;
        float dv = dinv[node];
        float4 v = *reinterpret_cast<const float4*>(x + f);
        uint2 o;
        o.x = pk_bf16(v.x * dv, v.y * dv);
        o.y = pk_bf16(v.z * dv, v.w * dv);
        *reinterpret_cast<uint2*>(y + ((size_t)(k >> 5) * N + node) * 32 + (k & 31)) = o;
    }
}

// ---------- chunked agg: z[c][i] = bf16(dinv[i]*(y[c][i] + sum y[c][src])) ----------
// chunk-major [NC][N][32]; chunk = blockIdx.x % NC rides block->XCD round-robin
template<int NC>
__global__ __launch_bounds__(256) void agg_kernel(const ushort* __restrict__ y,
                                                  const float* __restrict__ dinv,
                                                  const int* __restrict__ row_ptr,
                                                  const ushort* __restrict__ ssrc,
                                                  ushort* __restrict__ zout, int n) {
    int wave = threadIdx.x >> 6;
    int lane = threadIdx.x & 63;
    int chunk = blockIdx.x % NC;
    int node = (blockIdx.x / NC) * 4 + wave;
    if (node >= n) return;
    int es = lane >> 4;          // edge slot 0..3
    int fd = lane & 15;          // feature dword (2 bf16)
    const size_t plane = (size_t)chunk * n;

    float a0 = 0.f, a1 = 0.f;
    if (es == 0) {
        uint32_t u = *reinterpret_cast<const uint32_t*>(y + (plane + node) * 32 + fd * 2);
        bf2acc(u, a0, a1);
    }
    int beg = row_ptr[node], end = row_ptr[node + 1];
    for (int e = beg; e < end; e += 4) {
        int ee = e + es;
        uint32_t u = 0;
        if (ee < end) {
            int s = ssrc[ee];
            u = *reinterpret_cast<const uint32_t*>(y + (plane + s) * 32 + fd * 2);
        }
        bf2acc(u, a0, a1);
    }
    a0 += __shfl_xor(a0, 16); a1 += __shfl_xor(a1, 16);
    a0 += __shfl_xor(a0, 32); a1 += __shfl_xor(a1, 32);
    if (es == 0) {
        float dv = dinv[node];
        *reinterpret_cast<uint32_t*>(zout + (plane + node) * 32 + fd * 2) = pk_bf16(dv * a0, dv * a1);
    }
}

// ---------- MFMA GEMM: chunk-major A [K/32][M][32], C [256/32][M][32] ----------
template<bool RELU>
__global__ __launch_bounds__(256) void mfma_gemm(const ushort* __restrict__ A,
                                                 const ushort* __restrict__ Bhi,
                                                 const ushort* __restrict__ Blo,
                                                 const float* __restrict__ bias,
                                                 const float* __restrict__ dinv,
                                                 ushort* __restrict__ C, int M, int K) {
    constexpr int BM = 128, BN = 64, BK = 64;
    constexpr int LDK = BK + 8;
    __shared__ ushort As[BM][LDK];
    __shared__ ushort Bh[BN][LDK];
    __shared__ ushort Bl[BN][LDK];

    const int tid = threadIdx.x;
    const int w = tid >> 6;
    const int l = tid & 63;
    const int lr = l & 15;
    const int lk = (l >> 4) * 8;
    const int bm = blockIdx.x * BM;
    const int bn = blockIdx.y * BN;

    f32x4 acc[8];
    #pragma unroll
    for (int i = 0; i < 8; ++i) acc[i] = (f32x4){0.f, 0.f, 0.f, 0.f};

    for (int k0 = 0; k0 < K; k0 += BK) {
        #pragma unroll
        for (int p = 0; p < 4; ++p) {           // A: 1024 slots x 8 bf16
            int g = tid + p * 256;
            int r = g >> 3;
            int c = (g & 7) << 3;
            int grow = bm + r;
            int gk = k0 + c;
            uint4 va = make_uint4(0u, 0u, 0u, 0u);
            if (grow < M)
                va = *reinterpret_cast<const uint4*>(A + ((size_t)(gk >> 5) * M + grow) * 32 + (gk & 31));
            *reinterpret_cast<uint4*>(&As[r][c]) = va;
        }
        #pragma unroll
        for (int p = 0; p < 2; ++p) {           // B hi/lo: 512 slots each
            int g = tid + p * 256;
            int r = g >> 3;
            int c = (g & 7) << 3;
            *reinterpret_cast<uint4*>(&Bh[r][c]) =
                *reinterpret_cast<const uint4*>(Bhi + (size_t)(bn + r) * K + k0 + c);
            *reinterpret_cast<uint4*>(&Bl[r][c]) =
                *reinterpret_cast<const uint4*>(Blo + (size_t)(bn + r) * K + k0 + c);
        }
        __syncthreads();
        #pragma unroll
        for (int kk = 0; kk < BK; kk += 32) {
            bf16x8 bh = *reinterpret_cast<const bf16x8*>(&Bh[w * 16 + lr][kk + lk]);
            bf16x8 bl = *reinterpret_cast<const bf16x8*>(&Bl[w * 16 + lr][kk + lk]);
            #pragma unroll
            for (int r16 = 0; r16 < 8; ++r16) {
                bf16x8 a = *reinterpret_cast<const bf16x8*>(&As[r16 * 16 + lr][kk + lk]);
                acc[r16] = __builtin_amdgcn_mfma_f32_16x16x32_bf16(a, bh, acc[r16], 0, 0, 0);
                acc[r16] = __builtin_amdgcn_mfma_f32_16x16x32_bf16(a, bl, acc[r16], 0, 0, 0);
            }
        }
        __syncthreads();
    }

    int col = bn + w * 16 + lr;
    int cc = col >> 5, co = col & 31;
    float bv = bias[col];
    #pragma unroll
    for (int r16 = 0; r16 < 8; ++r16) {
        #pragma unroll
        for (int j = 0; j < 4; ++j) {
            int row = bm + r16 * 16 + (l >> 4) * 4 + j;
            if (row < M) {
                float v = acc[r16][j] + bv;
                if (RELU) v = fmaxf(v, 0.f);
                v *= dinv[row];
                C[((size_t)cc * M + row) * 32 + co] = bf16r(v);
            }
        }
    }
}

// ---------- mean-pool over chunk-major bf16 [8][N][32] ----------
__global__ __launch_bounds__(256) void pool_kernel(const ushort* __restrict__ z,
                                                   const int* __restrict__ batch,
                                                   float* __restrict__ sums,
                                                   int* __restrict__ gcnt, int n) {
    constexpr int NCH = 128;
    int t = threadIdx.x;
    int base = blockIdx.x * NCH;
    if (base >= n) return;
    int endn = min(base + NCH, n);
    size_t poff = (size_t)(t >> 5) * n;
    int co = t & 31;
    int cur = batch[base];
    float local = 0.f;
    int cl = 0;
    for (int i = base; i < endn; ++i) {
        int g = batch[i];
        if (g != cur) {
            atomicAdd(&sums[cur * H + t], local);
            if (t == 0) atomicAdd(&gcnt[cur], cl);
            local = 0.f; cl = 0; cur = g;
        }
        local += bf2f(z[(poff + i) * 32 + co]);
        cl++;
    }
    atomicAdd(&sums[cur * H + t], local);
    if (t == 0) atomicAdd(&gcnt[cur], cl);
}

// ---------- head ----------
__global__ __launch_bounds__(256) void head_kernel(const float* __restrict__ sums,
                                                   const int* __restrict__ gcnt,
                                                   const float* __restrict__ w3, const float* __restrict__ b3,
                                                   const float* __restrict__ l1w, const float* __restrict__ l1b,
                                                   const float* __restrict__ l2w, const float* __restrict__ l2b,
                                                   float* __restrict__ out) {
    __shared__ float pooled[H];
    __shared__ float t3[H];
    __shared__ float mid[H / 2];
    int g = blockIdx.x, t = threadIdx.x;
    float c = (float)max(gcnt[g], 1);
    pooled[t] = sums[g * H + t] / c;
    __syncthreads();
    float a = b3[t];
    for (int k = 0; k < H; ++k) a += pooled[k] * w3[k * H + t];
    t3[t] = a;
    __syncthreads();
    if (t < H / 2) {
        float m = l1b[t];
        for (int k = 0; k < H; ++k) m += t3[k] * l1w[k * (H / 2) + t];
        mid[t] = m;
    }
    __syncthreads();
    if (t < 3) {
        float o = l2b[t];
        for (int k = 0; k < H / 2; ++k) o += mid[k] * l2w[k * 3 + t];
        out[g * 3 + t] = o;
    }
}

extern "C" void kernel_launch(void* const* d_in, const int* in_sizes, int n_in,
                              void* d_out, int out_size, void* d_ws, size_t ws_size,
                              hipStream_t stream) {
    const float* x   = (const float*)d_in[0];
    const int*   ei  = (const int*)d_in[2];
    const int*   bat = (const int*)d_in[3];
    const float* w1  = (const float*)d_in[4];
    const float* b1  = (const float*)d_in[5];
    const float* w2  = (const float*)d_in[6];
    const float* b2  = (const float*)d_in[7];
    const float* w3  = (const float*)d_in[8];
    const float* b3  = (const float*)d_in[9];
    const float* l1w = (const float*)d_in[10];
    const float* l1b = (const float*)d_in[11];
    const float* l2w = (const float*)d_in[12];
    const float* l2b = (const float*)d_in[13];
    float* out = (float*)d_out;

    const int N = in_sizes[0] / 128;   // 50000
    const int E = in_sizes[2] / 2;     // 800000
    const int NB = (N + 255) / 256;

    char* ws = (char*)d_ws;
    size_t off = 0;
    auto alloc = [&](size_t bytes) {
        void* p = ws + off;
        off = (off + bytes + 255) & ~(size_t)255;
        return p;
    };
    ushort* yb     = (ushort*)alloc((size_t)N * H * 2);   // bf16 ping (chunk-major)
    ushort* z16    = (ushort*)alloc((size_t)N * H * 2);   // bf16 pong (chunk-major)
    int*    cnt    = (int*)alloc((size_t)N * 4);
    float*  dinv   = (float*)alloc((size_t)N * 4);
    int*    row_ptr= (int*)alloc((size_t)(N + 1) * 4);
    int*    fill   = (int*)alloc((size_t)N * 4);
    ushort* ssrc   = (ushort*)alloc((size_t)E * 2);       // u16 indices (N < 65536)
    int*    bsum   = (int*)alloc(256 * 4);
    int*    boff   = (int*)alloc(256 * 4);
    ushort* wt1h   = (ushort*)alloc((size_t)128 * 256 * 2);
    ushort* wt1l   = (ushort*)alloc((size_t)128 * 256 * 2);
    ushort* wt2h   = (ushort*)alloc((size_t)256 * 256 * 2);
    ushort* wt2l   = (ushort*)alloc((size_t)256 * 256 * 2);
    float*  sums   = (float*)alloc((size_t)NG * H * 4);
    int*    gcnt   = (int*)alloc((size_t)NG * 4);

    hipMemsetAsync(cnt, 0, (size_t)N * 4, stream);

    hist_kernel<<<(E + 255) / 256, 256, 0, stream>>>(ei + E, cnt, E);
    scanA<<<NB, 256, 0, stream>>>(cnt, bsum, dinv, N);
    scanB<<<1, 256, 0, stream>>>(bsum, boff, row_ptr + N, NB, sums, gcnt);
    scanC<<<NB, 256, 0, stream>>>(cnt, boff, row_ptr, fill, N);
    // fused: wconv + scatter + prescale
    int sp_blocks = (N * 32 + 255) / 256;
    wsp_kernel<<<WCONV_BLOCKS + sp_blocks, 256, 0, stream>>>(
        w1, wt1h, wt1l, w2, wt2h, wt2l,
        ei, ei + E, fill, ssrc, E, x, dinv, yb, N);

    // layer 1: chunked agg (4 chunks, width 128) -> MFMA GEMM 128->256
    agg_kernel<4><<<((N + 3) / 4) * 4, 256, 0, stream>>>(yb, dinv, row_ptr, ssrc, z16, N);
    mfma_gemm<true><<<dim3((N + 127) / 128, 4), 256, 0, stream>>>(z16, wt1h, wt1l, b1, dinv, yb, N, 128);

    // layer 2: chunked agg (8 chunks, width 256)
    agg_kernel<8><<<((N + 3) / 4) * 8, 256, 0, stream>>>(yb, dinv, row_ptr, ssrc, z16, N);
    mfma_gemm<true><<<dim3((N + 127) / 128, 4), 256, 0, stream>>>(z16, wt2h, wt2l, b2, dinv, yb, N, 256);

    // layer 3: agg only (W3 folded into head)
    agg_kernel<8><<<((N + 3) / 4) * 8, 256, 0, stream>>>(yb, dinv, row_ptr, ssrc, z16, N);

    pool_kernel<<<(N + 127) / 128, 256, 0, stream>>>(z16, bat, sums, gcnt, N);
    head_kernel<<<NG, 256, 0, stream>>>(sums, gcnt, w3, b3, l1w, l1b, l2w, l2b, out);
}

// Round 9
// 622.418 us; speedup vs baseline: 1.1398x; 1.1398x over previous
//
#include <hip/hip_runtime.h>
#include <cstdint>

constexpr int NG = 64;     // graphs
constexpr int H  = 256;    // hidden width

typedef __bf16 bf16x8 __attribute__((ext_vector_type(8)));
typedef float  f32x4  __attribute__((ext_vector_type(4)));

__device__ __forceinline__ uint32_t pk_bf16(float a, float b) {
    uint32_t ua = __builtin_bit_cast(uint32_t, a);
    uint32_t ub = __builtin_bit_cast(uint32_t, b);
    ua += 0x7fffu + ((ua >> 16) & 1u);
    ub += 0x7fffu + ((ub >> 16) & 1u);
    return (ua >> 16) | (ub & 0xffff0000u);
}
__device__ __forceinline__ ushort bf16r(float x) {
    uint32_t u = __builtin_bit_cast(uint32_t, x);
    u += 0x7fffu + ((u >> 16) & 1u);
    return (ushort)(u >> 16);
}
__device__ __forceinline__ float bf2f(ushort h) {
    return __builtin_bit_cast(float, ((uint32_t)h) << 16);
}
__device__ __forceinline__ void bf2acc(uint32_t u, float& a0, float& a1) {
    a0 += __builtin_bit_cast(float, u << 16);
    a1 += __builtin_bit_cast(float, u & 0xffff0000u);
}

// ---------- degree histogram ----------
__global__ void hist_kernel(const int* __restrict__ dst, int* __restrict__ cnt, int E) {
    int e = blockIdx.x * blockDim.x + threadIdx.x;
    if (e < E) atomicAdd(&cnt[dst[e]], 1);
}

// ---------- scanA + dinv ----------
__global__ __launch_bounds__(256) void scanA(const int* __restrict__ cnt, int* __restrict__ bsum,
                                             float* __restrict__ dinv, int n) {
    __shared__ int sh[256];
    int t = threadIdx.x, i = blockIdx.x * 256 + t;
    int v = (i < n) ? cnt[i] : 0;
    if (i < n) dinv[i] = rsqrtf((float)(v + 1));
    sh[t] = v;
    __syncthreads();
    for (int off = 128; off > 0; off >>= 1) {
        if (t < off) sh[t] += sh[t + off];
        __syncthreads();
    }
    if (t == 0) bsum[blockIdx.x] = sh[0];
}

// ---------- scanB + zero sums/gcnt ----------
__global__ __launch_bounds__(256) void scanB(const int* __restrict__ bsum, int* __restrict__ boff,
                                             int* __restrict__ total_out, int nb,
                                             float* __restrict__ sums, int* __restrict__ gcnt) {
    __shared__ int sh[256];
    int t = threadIdx.x;
    for (int i = t; i < NG * H; i += 256) sums[i] = 0.f;
    if (t < NG) gcnt[t] = 0;
    int v = (t < nb) ? bsum[t] : 0;
    sh[t] = v;
    __syncthreads();
    for (int off = 1; off < 256; off <<= 1) {
        int a = (t >= off) ? sh[t - off] : 0;
        __syncthreads();
        sh[t] += a;
        __syncthreads();
    }
    if (t < nb) boff[t] = sh[t] - v;
    if (t == nb - 1) *total_out = sh[t];
}

__global__ __launch_bounds__(256) void scanC(const int* __restrict__ cnt, const int* __restrict__ boff,
                                             int* __restrict__ row_ptr, int* __restrict__ fill, int n) {
    __shared__ int sh[256];
    int t = threadIdx.x, i = blockIdx.x * 256 + t;
    int v = (i < n) ? cnt[i] : 0;
    sh[t] = v;
    __syncthreads();
    for (int off = 1; off < 256; off <<= 1) {
        int a = (t >= off) ? sh[t - off] : 0;
        __syncthreads();
        sh[t] += a;
        __syncthreads();
    }
    if (i < n) {
        int excl = boff[blockIdx.x] + sh[t] - v;
        row_ptr[i] = excl;
        fill[i] = excl;
    }
}

// ---------- fused: wconv (both W) + counting-sort scatter + prescale ----------
// y layout: chunk-major [4][N][32] bf16 (width 128)
constexpr int WCONV_BLOCKS = (128 * 256 + 256 * 256) / 256;   // 384
__global__ void wsp_kernel(const float* __restrict__ w1, ushort* __restrict__ h1, ushort* __restrict__ l1,
                           const float* __restrict__ w2, ushort* __restrict__ h2, ushort* __restrict__ l2,
                           const int* __restrict__ src, const int* __restrict__ dst,
                           int* __restrict__ fill, ushort* __restrict__ ssrc, int E,
                           const float* __restrict__ x, const float* __restrict__ dinv,
                           ushort* __restrict__ y, int N) {
    if (blockIdx.x < WCONV_BLOCKS) {
        int idx = blockIdx.x * 256 + threadIdx.x;
        const float* w; ushort *hi, *lo; int K;
        if (idx < 128 * 256) { w = w1; hi = h1; lo = l1; K = 128; }
        else { idx -= 128 * 256; w = w2; hi = h2; lo = l2; K = 256; }
        int k = idx / 256, n = idx & 255;
        float v = w[idx];
        ushort h = bf16r(v);
        float r = v - bf2f(h);
        hi[n * K + k] = h;
        lo[n * K + k] = bf16r(r);
        return;
    }
    int i = (blockIdx.x - WCONV_BLOCKS) * 256 + threadIdx.x;
    if (i < E) {
        int pos = atomicAdd(&fill[dst[i]], 1);
        ssrc[pos] = (ushort)src[i];
    }
    int np4 = N * 32;   // N*128/4
    if (i < np4) {
        int f = i * 4;
        int node = f >> 7;
        int k = f & 127;
        float dv = dinv[node];
        float4 v = *reinterpret_cast<const float4*>(x + f);
        uint2 o;
        o.x = pk_bf16(v.x * dv, v.y * dv);
        o.y = pk_bf16(v.z * dv, v.w * dv);
        *reinterpret_cast<uint2*>(y + ((size_t)(k >> 5) * N + node) * 32 + (k & 31)) = o;
    }
}

// ---------- chunked agg v2: 8 edge-slots x 8 lanes (uint2), unroll x2 ----------
// chunk-major [NC][N][32]; chunk = blockIdx.x % NC rides block->XCD round-robin
template<int NC>
__global__ __launch_bounds__(256) void agg_kernel(const ushort* __restrict__ y,
                                                  const float* __restrict__ dinv,
                                                  const int* __restrict__ row_ptr,
                                                  const ushort* __restrict__ ssrc,
                                                  ushort* __restrict__ zout, int n) {
    int wave = threadIdx.x >> 6;
    int lane = threadIdx.x & 63;
    int chunk = blockIdx.x % NC;
    int node = (blockIdx.x / NC) * 4 + wave;
    if (node >= n) return;
    int slot = lane >> 3;        // edge slot 0..7
    int fd   = lane & 7;         // uint2 (4 bf16) within 64B row
    const ushort* yc = y + (size_t)chunk * n * 32;

    float a0 = 0.f, a1 = 0.f, a2 = 0.f, a3 = 0.f;
    if (slot == 0) {     // self term on slot 0
        uint2 u = *reinterpret_cast<const uint2*>(yc + node * 32 + fd * 4);
        bf2acc(u.x, a0, a1); bf2acc(u.y, a2, a3);
    }
    int beg = row_ptr[node], end = row_ptr[node + 1];
    int e = beg;
    // 16 edges per iteration: 2 independent 64B gathers in flight per lane-slot
    for (; e + 16 <= end; e += 16) {
        int s0 = ssrc[e + slot];
        int s1 = ssrc[e + 8 + slot];
        uint2 u0 = *reinterpret_cast<const uint2*>(yc + s0 * 32 + fd * 4);
        uint2 u1 = *reinterpret_cast<const uint2*>(yc + s1 * 32 + fd * 4);
        bf2acc(u0.x, a0, a1); bf2acc(u0.y, a2, a3);
        bf2acc(u1.x, a0, a1); bf2acc(u1.y, a2, a3);
    }
    for (; e < end; e += 8) {
        int ee = e + slot;
        uint2 u = make_uint2(0u, 0u);
        if (ee < end) {
            int s = ssrc[ee];
            u = *reinterpret_cast<const uint2*>(yc + s * 32 + fd * 4);
        }
        bf2acc(u.x, a0, a1); bf2acc(u.y, a2, a3);
    }
    // reduce across the 8 slots (lane bits 3,4,5)
    a0 += __shfl_xor(a0, 8);  a1 += __shfl_xor(a1, 8);  a2 += __shfl_xor(a2, 8);  a3 += __shfl_xor(a3, 8);
    a0 += __shfl_xor(a0, 16); a1 += __shfl_xor(a1, 16); a2 += __shfl_xor(a2, 16); a3 += __shfl_xor(a3, 16);
    a0 += __shfl_xor(a0, 32); a1 += __shfl_xor(a1, 32); a2 += __shfl_xor(a2, 32); a3 += __shfl_xor(a3, 32);
    if (slot == 0) {
        float dv = dinv[node];
        uint2 o;
        o.x = pk_bf16(dv * a0, dv * a1);
        o.y = pk_bf16(dv * a2, dv * a3);
        *reinterpret_cast<uint2*>(zout + ((size_t)chunk * n + node) * 32 + fd * 4) = o;
    }
}

// ---------- MFMA GEMM: chunk-major A [K/32][M][32], C [256/32][M][32] ----------
template<bool RELU>
__global__ __launch_bounds__(256) void mfma_gemm(const ushort* __restrict__ A,
                                                 const ushort* __restrict__ Bhi,
                                                 const ushort* __restrict__ Blo,
                                                 const float* __restrict__ bias,
                                                 const float* __restrict__ dinv,
                                                 ushort* __restrict__ C, int M, int K) {
    constexpr int BM = 128, BN = 64, BK = 64;
    constexpr int LDK = BK + 8;
    __shared__ ushort As[BM][LDK];
    __shared__ ushort Bh[BN][LDK];
    __shared__ ushort Bl[BN][LDK];

    const int tid = threadIdx.x;
    const int w = tid >> 6;
    const int l = tid & 63;
    const int lr = l & 15;
    const int lk = (l >> 4) * 8;
    const int bm = blockIdx.x * BM;
    const int bn = blockIdx.y * BN;

    f32x4 acc[8];
    #pragma unroll
    for (int i = 0; i < 8; ++i) acc[i] = (f32x4){0.f, 0.f, 0.f, 0.f};

    for (int k0 = 0; k0 < K; k0 += BK) {
        #pragma unroll
        for (int p = 0; p < 4; ++p) {           // A: 1024 slots x 8 bf16
            int g = tid + p * 256;
            int r = g >> 3;
            int c = (g & 7) << 3;
            int grow = bm + r;
            int gk = k0 + c;
            uint4 va = make_uint4(0u, 0u, 0u, 0u);
            if (grow < M)
                va = *reinterpret_cast<const uint4*>(A + ((size_t)(gk >> 5) * M + grow) * 32 + (gk & 31));
            *reinterpret_cast<uint4*>(&As[r][c]) = va;
        }
        #pragma unroll
        for (int p = 0; p < 2; ++p) {           // B hi/lo: 512 slots each
            int g = tid + p * 256;
            int r = g >> 3;
            int c = (g & 7) << 3;
            *reinterpret_cast<uint4*>(&Bh[r][c]) =
                *reinterpret_cast<const uint4*>(Bhi + (size_t)(bn + r) * K + k0 + c);
            *reinterpret_cast<uint4*>(&Bl[r][c]) =
                *reinterpret_cast<const uint4*>(Blo + (size_t)(bn + r) * K + k0 + c);
        }
        __syncthreads();
        #pragma unroll
        for (int kk = 0; kk < BK; kk += 32) {
            bf16x8 bh = *reinterpret_cast<const bf16x8*>(&Bh[w * 16 + lr][kk + lk]);
            bf16x8 bl = *reinterpret_cast<const bf16x8*>(&Bl[w * 16 + lr][kk + lk]);
            #pragma unroll
            for (int r16 = 0; r16 < 8; ++r16) {
                bf16x8 a = *reinterpret_cast<const bf16x8*>(&As[r16 * 16 + lr][kk + lk]);
                acc[r16] = __builtin_amdgcn_mfma_f32_16x16x32_bf16(a, bh, acc[r16], 0, 0, 0);
                acc[r16] = __builtin_amdgcn_mfma_f32_16x16x32_bf16(a, bl, acc[r16], 0, 0, 0);
            }
        }
        __syncthreads();
    }

    int col = bn + w * 16 + lr;
    int cc = col >> 5, co = col & 31;
    float bv = bias[col];
    #pragma unroll
    for (int r16 = 0; r16 < 8; ++r16) {
        #pragma unroll
        for (int j = 0; j < 4; ++j) {
            int row = bm + r16 * 16 + (l >> 4) * 4 + j;
            if (row < M) {
                float v = acc[r16][j] + bv;
                if (RELU) v = fmaxf(v, 0.f);
                v *= dinv[row];
                C[((size_t)cc * M + row) * 32 + co] = bf16r(v);
            }
        }
    }
}

// ---------- mean-pool over chunk-major bf16 [8][N][32] ----------
__global__ __launch_bounds__(256) void pool_kernel(const ushort* __restrict__ z,
                                                   const int* __restrict__ batch,
                                                   float* __restrict__ sums,
                                                   int* __restrict__ gcnt, int n) {
    constexpr int NCH = 128;
    int t = threadIdx.x;
    int base = blockIdx.x * NCH;
    if (base >= n) return;
    int endn = min(base + NCH, n);
    size_t poff = (size_t)(t >> 5) * n;
    int co = t & 31;
    int cur = batch[base];
    float local = 0.f;
    int cl = 0;
    for (int i = base; i < endn; ++i) {
        int g = batch[i];
        if (g != cur) {
            atomicAdd(&sums[cur * H + t], local);
            if (t == 0) atomicAdd(&gcnt[cur], cl);
            local = 0.f; cl = 0; cur = g;
        }
        local += bf2f(z[(poff + i) * 32 + co]);
        cl++;
    }
    atomicAdd(&sums[cur * H + t], local);
    if (t == 0) atomicAdd(&gcnt[cur], cl);
}

// ---------- head ----------
__global__ __launch_bounds__(256) void head_kernel(const float* __restrict__ sums,
                                                   const int* __restrict__ gcnt,
                                                   const float* __restrict__ w3, const float* __restrict__ b3,
                                                   const float* __restrict__ l1w, const float* __restrict__ l1b,
                                                   const float* __restrict__ l2w, const float* __restrict__ l2b,
                                                   float* __restrict__ out) {
    __shared__ float pooled[H];
    __shared__ float t3[H];
    __shared__ float mid[H / 2];
    int g = blockIdx.x, t = threadIdx.x;
    float c = (float)max(gcnt[g], 1);
    pooled[t] = sums[g * H + t] / c;
    __syncthreads();
    float a = b3[t];
    for (int k = 0; k < H; ++k) a += pooled[k] * w3[k * H + t];
    t3[t] = a;
    __syncthreads();
    if (t < H / 2) {
        float m = l1b[t];
        for (int k = 0; k < H; ++k) m += t3[k] * l1w[k * (H / 2) + t];
        mid[t] = m;
    }
    __syncthreads();
    if (t < 3) {
        float o = l2b[t];
        for (int k = 0; k < H / 2; ++k) o += mid[k] * l2w[k * 3 + t];
        out[g * 3 + t] = o;
    }
}

extern "C" void kernel_launch(void* const* d_in, const int* in_sizes, int n_in,
                              void* d_out, int out_size, void* d_ws, size_t ws_size,
                              hipStream_t stream) {
    const float* x   = (const float*)d_in[0];
    const int*   ei  = (const int*)d_in[2];
    const int*   bat = (const int*)d_in[3];
    const float* w1  = (const float*)d_in[4];
    const float* b1  = (const float*)d_in[5];
    const float* w2  = (const float*)d_in[6];
    const float* b2  = (const float*)d_in[7];
    const float* w3  = (const float*)d_in[8];
    const float* b3  = (const float*)d_in[9];
    const float* l1w = (const float*)d_in[10];
    const float* l1b = (const float*)d_in[11];
    const float* l2w = (const float*)d_in[12];
    const float* l2b = (const float*)d_in[13];
    float* out = (float*)d_out;

    const int N = in_sizes[0] / 128;   // 50000
    const int E = in_sizes[2] / 2;     // 800000
    const int NB = (N + 255) / 256;

    char* ws = (char*)d_ws;
    size_t off = 0;
    auto alloc = [&](size_t bytes) {
        void* p = ws + off;
        off = (off + bytes + 255) & ~(size_t)255;
        return p;
    };
    ushort* yb     = (ushort*)alloc((size_t)N * H * 2);   // bf16 ping (chunk-major)
    ushort* z16    = (ushort*)alloc((size_t)N * H * 2);   // bf16 pong (chunk-major)
    int*    cnt    = (int*)alloc((size_t)N * 4);
    float*  dinv   = (float*)alloc((size_t)N * 4);
    int*    row_ptr= (int*)alloc((size_t)(N + 1) * 4);
    int*    fill   = (int*)alloc((size_t)N * 4);
    ushort* ssrc   = (ushort*)alloc((size_t)E * 2);       // u16 indices (N < 65536)
    int*    bsum   = (int*)alloc(256 * 4);
    int*    boff   = (int*)alloc(256 * 4);
    ushort* wt1h   = (ushort*)alloc((size_t)128 * 256 * 2);
    ushort* wt1l   = (ushort*)alloc((size_t)128 * 256 * 2);
    ushort* wt2h   = (ushort*)alloc((size_t)256 * 256 * 2);
    ushort* wt2l   = (ushort*)alloc((size_t)256 * 256 * 2);
    float*  sums   = (float*)alloc((size_t)NG * H * 4);
    int*    gcnt   = (int*)alloc((size_t)NG * 4);

    hipMemsetAsync(cnt, 0, (size_t)N * 4, stream);

    hist_kernel<<<(E + 255) / 256, 256, 0, stream>>>(ei + E, cnt, E);
    scanA<<<NB, 256, 0, stream>>>(cnt, bsum, dinv, N);
    scanB<<<1, 256, 0, stream>>>(bsum, boff, row_ptr + N, NB, sums, gcnt);
    scanC<<<NB, 256, 0, stream>>>(cnt, boff, row_ptr, fill, N);
    // fused: wconv + scatter + prescale
    int sp_blocks = (N * 32 + 255) / 256;
    wsp_kernel<<<WCONV_BLOCKS + sp_blocks, 256, 0, stream>>>(
        w1, wt1h, wt1l, w2, wt2h, wt2l,
        ei, ei + E, fill, ssrc, E, x, dinv, yb, N);

    // layer 1: chunked agg (4 chunks, width 128) -> MFMA GEMM 128->256
    agg_kernel<4><<<((N + 3) / 4) * 4, 256, 0, stream>>>(yb, dinv, row_ptr, ssrc, z16, N);
    mfma_gemm<true><<<dim3((N + 127) / 128, 4), 256, 0, stream>>>(z16, wt1h, wt1l, b1, dinv, yb, N, 128);

    // layer 2: chunked agg (8 chunks, width 256)
    agg_kernel<8><<<((N + 3) / 4) * 8, 256, 0, stream>>>(yb, dinv, row_ptr, ssrc, z16, N);
    mfma_gemm<true><<<dim3((N + 127) / 128, 4), 256, 0, stream>>>(z16, wt2h, wt2l, b2, dinv, yb, N, 256);

    // layer 3: agg only (W3 folded into head)
    agg_kernel<8><<<((N + 3) / 4) * 8, 256, 0, stream>>>(yb, dinv, row_ptr, ssrc, z16, N);

    pool_kernel<<<(N + 127) / 128, 256, 0, stream>>>(z16, bat, sums, gcnt, N);
    head_kernel<<<NG, 256, 0, stream>>>(sums, gcnt, w3, b3, l1w, l1b, l2w, l2b, out);
}

// Round 10
// 470.546 us; speedup vs baseline: 1.5077x; 1.3228x over previous
//
#include <hip/hip_runtime.h>
#include <cstdint>

constexpr int NG = 64;     // graphs
constexpr int H  = 256;    // hidden width

typedef __bf16 bf16x8 __attribute__((ext_vector_type(8)));
typedef float  f32x4  __attribute__((ext_vector_type(4)));

__device__ __forceinline__ uint32_t pk_bf16(float a, float b) {
    uint32_t ua = __builtin_bit_cast(uint32_t, a);
    uint32_t ub = __builtin_bit_cast(uint32_t, b);
    ua += 0x7fffu + ((ua >> 16) & 1u);
    ub += 0x7fffu + ((ub >> 16) & 1u);
    return (ua >> 16) | (ub & 0xffff0000u);
}
__device__ __forceinline__ ushort bf16r(float x) {
    uint32_t u = __builtin_bit_cast(uint32_t, x);
    u += 0x7fffu + ((u >> 16) & 1u);
    return (ushort)(u >> 16);
}
__device__ __forceinline__ float bf2f(ushort h) {
    return __builtin_bit_cast(float, ((uint32_t)h) << 16);
}
__device__ __forceinline__ void bf2acc(uint32_t u, float& a0, float& a1) {
    a0 += __builtin_bit_cast(float, u << 16);
    a1 += __builtin_bit_cast(float, u & 0xffff0000u);
}

// ---------- degree histogram ----------
__global__ void hist_kernel(const int* __restrict__ dst, int* __restrict__ cnt, int E) {
    int e = blockIdx.x * blockDim.x + threadIdx.x;
    if (e < E) atomicAdd(&cnt[dst[e]], 1);
}

// ---------- scanA + dinv ----------
__global__ __launch_bounds__(256) void scanA(const int* __restrict__ cnt, int* __restrict__ bsum,
                                             float* __restrict__ dinv, int n) {
    __shared__ int sh[256];
    int t = threadIdx.x, i = blockIdx.x * 256 + t;
    int v = (i < n) ? cnt[i] : 0;
    if (i < n) dinv[i] = rsqrtf((float)(v + 1));
    sh[t] = v;
    __syncthreads();
    for (int off = 128; off > 0; off >>= 1) {
        if (t < off) sh[t] += sh[t + off];
        __syncthreads();
    }
    if (t == 0) bsum[blockIdx.x] = sh[0];
}

// ---------- scanB + zero sums/gcnt ----------
__global__ __launch_bounds__(256) void scanB(const int* __restrict__ bsum, int* __restrict__ boff,
                                             int* __restrict__ total_out, int nb,
                                             float* __restrict__ sums, int* __restrict__ gcnt) {
    __shared__ int sh[256];
    int t = threadIdx.x;
    for (int i = t; i < NG * H; i += 256) sums[i] = 0.f;
    if (t < NG) gcnt[t] = 0;
    int v = (t < nb) ? bsum[t] : 0;
    sh[t] = v;
    __syncthreads();
    for (int off = 1; off < 256; off <<= 1) {
        int a = (t >= off) ? sh[t - off] : 0;
        __syncthreads();
        sh[t] += a;
        __syncthreads();
    }
    if (t < nb) boff[t] = sh[t] - v;
    if (t == nb - 1) *total_out = sh[t];
}

__global__ __launch_bounds__(256) void scanC(const int* __restrict__ cnt, const int* __restrict__ boff,
                                             int* __restrict__ row_ptr, int* __restrict__ fill, int n) {
    __shared__ int sh[256];
    int t = threadIdx.x, i = blockIdx.x * 256 + t;
    int v = (i < n) ? cnt[i] : 0;
    sh[t] = v;
    __syncthreads();
    for (int off = 1; off < 256; off <<= 1) {
        int a = (t >= off) ? sh[t - off] : 0;
        __syncthreads();
        sh[t] += a;
        __syncthreads();
    }
    if (i < n) {
        int excl = boff[blockIdx.x] + sh[t] - v;
        row_ptr[i] = excl;
        fill[i] = excl;
    }
}

// ---------- fused: wconv (both W) + counting-sort scatter + prescale ----------
// y layout: chunk-major [4][N][32] bf16 (width 128)
constexpr int WCONV_BLOCKS = (128 * 256 + 256 * 256) / 256;   // 384
__global__ void wsp_kernel(const float* __restrict__ w1, ushort* __restrict__ h1, ushort* __restrict__ l1,
                           const float* __restrict__ w2, ushort* __restrict__ h2, ushort* __restrict__ l2,
                           const int* __restrict__ src, const int* __restrict__ dst,
                           int* __restrict__ fill, ushort* __restrict__ ssrc, int E,
                           const float* __restrict__ x, const float* __restrict__ dinv,
                           ushort* __restrict__ y, int N) {
    if (blockIdx.x < WCONV_BLOCKS) {
        int idx = blockIdx.x * 256 + threadIdx.x;
        const float* w; ushort *hi, *lo; int K;
        if (idx < 128 * 256) { w = w1; hi = h1; lo = l1; K = 128; }
        else { idx -= 128 * 256; w = w2; hi = h2; lo = l2; K = 256; }
        int k = idx / 256, n = idx & 255;
        float v = w[idx];
        ushort h = bf16r(v);
        float r = v - bf2f(h);
        hi[n * K + k] = h;
        lo[n * K + k] = bf16r(r);
        return;
    }
    int i = (blockIdx.x - WCONV_BLOCKS) * 256 + threadIdx.x;
    if (i < E) {
        int pos = atomicAdd(&fill[dst[i]], 1);
        ssrc[pos] = (ushort)src[i];
    }
    int np4 = N * 32;   // N*128/4
    if (i < np4) {
        int f = i * 4;
        int node = f >> 7;
        int k = f & 127;
        float dv = dinv[node];
        float4 v = *reinterpret_cast<const float4*>(x + f);
        uint2 o;
        o.x = pk_bf16(v.x * dv, v.y * dv);
        o.y = pk_bf16(v.z * dv, v.w * dv);
        *reinterpret_cast<uint2*>(y + ((size_t)(k >> 5) * N + node) * 32 + (k & 31)) = o;
    }
}

// ---------- chunked agg v3: wave = 8 nodes x 1 chunk; 8-lane group owns a full 64B row ----------
// chunk-major [NC][N][32]; chunk = blockIdx.x % NC rides block->XCD round-robin
template<int NC>
__global__ __launch_bounds__(256) void agg_kernel(const ushort* __restrict__ y,
                                                  const float* __restrict__ dinv,
                                                  const int* __restrict__ row_ptr,
                                                  const ushort* __restrict__ ssrc,
                                                  ushort* __restrict__ zout, int n) {
    int wave = threadIdx.x >> 6;             // 0..3
    int lane = threadIdx.x & 63;
    int grp  = lane >> 3;                    // node sub-index 0..7
    int fd   = lane & 7;                     // uint2 slot within 64B row
    int chunk = blockIdx.x % NC;
    int node  = (blockIdx.x / NC) * 32 + wave * 8 + grp;
    if (node >= n) return;
    const ushort* yc = y + (size_t)chunk * n * 32;

    float a0, a1, a2, a3;
    {   // self term
        uint2 u = *reinterpret_cast<const uint2*>(yc + (size_t)node * 32 + fd * 4);
        a0 = a1 = a2 = a3 = 0.f;
        bf2acc(u.x, a0, a1); bf2acc(u.y, a2, a3);
    }
    int beg = row_ptr[node], end = row_ptr[node + 1];
    int e = beg;
    for (; e + 2 <= end; e += 2) {           // 2 independent gathers in flight per group
        int s0 = ssrc[e], s1 = ssrc[e + 1];
        uint2 u0 = *reinterpret_cast<const uint2*>(yc + (size_t)s0 * 32 + fd * 4);
        uint2 u1 = *reinterpret_cast<const uint2*>(yc + (size_t)s1 * 32 + fd * 4);
        bf2acc(u0.x, a0, a1); bf2acc(u0.y, a2, a3);
        bf2acc(u1.x, a0, a1); bf2acc(u1.y, a2, a3);
    }
    if (e < end) {
        int s = ssrc[e];
        uint2 u = *reinterpret_cast<const uint2*>(yc + (size_t)s * 32 + fd * 4);
        bf2acc(u.x, a0, a1); bf2acc(u.y, a2, a3);
    }
    float dv = dinv[node];
    uint2 o;
    o.x = pk_bf16(dv * a0, dv * a1);
    o.y = pk_bf16(dv * a2, dv * a3);
    *reinterpret_cast<uint2*>(zout + ((size_t)chunk * n + node) * 32 + fd * 4) = o;
}

// ---------- MFMA GEMM: chunk-major A [K/32][M][32], C [256/32][M][32] ----------
template<bool RELU>
__global__ __launch_bounds__(256) void mfma_gemm(const ushort* __restrict__ A,
                                                 const ushort* __restrict__ Bhi,
                                                 const ushort* __restrict__ Blo,
                                                 const float* __restrict__ bias,
                                                 const float* __restrict__ dinv,
                                                 ushort* __restrict__ C, int M, int K) {
    constexpr int BM = 128, BN = 64, BK = 64;
    constexpr int LDK = BK + 8;
    __shared__ ushort As[BM][LDK];
    __shared__ ushort Bh[BN][LDK];
    __shared__ ushort Bl[BN][LDK];

    const int tid = threadIdx.x;
    const int w = tid >> 6;
    const int l = tid & 63;
    const int lr = l & 15;
    const int lk = (l >> 4) * 8;
    const int bm = blockIdx.x * BM;
    const int bn = blockIdx.y * BN;

    f32x4 acc[8];
    #pragma unroll
    for (int i = 0; i < 8; ++i) acc[i] = (f32x4){0.f, 0.f, 0.f, 0.f};

    for (int k0 = 0; k0 < K; k0 += BK) {
        #pragma unroll
        for (int p = 0; p < 4; ++p) {           // A: 1024 slots x 8 bf16
            int g = tid + p * 256;
            int r = g >> 3;
            int c = (g & 7) << 3;
            int grow = bm + r;
            int gk = k0 + c;
            uint4 va = make_uint4(0u, 0u, 0u, 0u);
            if (grow < M)
                va = *reinterpret_cast<const uint4*>(A + ((size_t)(gk >> 5) * M + grow) * 32 + (gk & 31));
            *reinterpret_cast<uint4*>(&As[r][c]) = va;
        }
        #pragma unroll
        for (int p = 0; p < 2; ++p) {           // B hi/lo: 512 slots each
            int g = tid + p * 256;
            int r = g >> 3;
            int c = (g & 7) << 3;
            *reinterpret_cast<uint4*>(&Bh[r][c]) =
                *reinterpret_cast<const uint4*>(Bhi + (size_t)(bn + r) * K + k0 + c);
            *reinterpret_cast<uint4*>(&Bl[r][c]) =
                *reinterpret_cast<const uint4*>(Blo + (size_t)(bn + r) * K + k0 + c);
        }
        __syncthreads();
        #pragma unroll
        for (int kk = 0; kk < BK; kk += 32) {
            bf16x8 bh = *reinterpret_cast<const bf16x8*>(&Bh[w * 16 + lr][kk + lk]);
            bf16x8 bl = *reinterpret_cast<const bf16x8*>(&Bl[w * 16 + lr][kk + lk]);
            #pragma unroll
            for (int r16 = 0; r16 < 8; ++r16) {
                bf16x8 a = *reinterpret_cast<const bf16x8*>(&As[r16 * 16 + lr][kk + lk]);
                acc[r16] = __builtin_amdgcn_mfma_f32_16x16x32_bf16(a, bh, acc[r16], 0, 0, 0);
                acc[r16] = __builtin_amdgcn_mfma_f32_16x16x32_bf16(a, bl, acc[r16], 0, 0, 0);
            }
        }
        __syncthreads();
    }

    int col = bn + w * 16 + lr;
    int cc = col >> 5, co = col & 31;
    float bv = bias[col];
    #pragma unroll
    for (int r16 = 0; r16 < 8; ++r16) {
        #pragma unroll
        for (int j = 0; j < 4; ++j) {
            int row = bm + r16 * 16 + (l >> 4) * 4 + j;
            if (row < M) {
                float v = acc[r16][j] + bv;
                if (RELU) v = fmaxf(v, 0.f);
                v *= dinv[row];
                C[((size_t)cc * M + row) * 32 + co] = bf16r(v);
            }
        }
    }
}

// ---------- mean-pool over chunk-major bf16 [8][N][32] ----------
__global__ __launch_bounds__(256) void pool_kernel(const ushort* __restrict__ z,
                                                   const int* __restrict__ batch,
                                                   float* __restrict__ sums,
                                                   int* __restrict__ gcnt, int n) {
    constexpr int NCH = 128;
    int t = threadIdx.x;
    int base = blockIdx.x * NCH;
    if (base >= n) return;
    int endn = min(base + NCH, n);
    size_t poff = (size_t)(t >> 5) * n;
    int co = t & 31;
    int cur = batch[base];
    float local = 0.f;
    int cl = 0;
    for (int i = base; i < endn; ++i) {
        int g = batch[i];
        if (g != cur) {
            atomicAdd(&sums[cur * H + t], local);
            if (t == 0) atomicAdd(&gcnt[cur], cl);
            local = 0.f; cl = 0; cur = g;
        }
        local += bf2f(z[(poff + i) * 32 + co]);
        cl++;
    }
    atomicAdd(&sums[cur * H + t], local);
    if (t == 0) atomicAdd(&gcnt[cur], cl);
}

// ---------- head ----------
__global__ __launch_bounds__(256) void head_kernel(const float* __restrict__ sums,
                                                   const int* __restrict__ gcnt,
                                                   const float* __restrict__ w3, const float* __restrict__ b3,
                                                   const float* __restrict__ l1w, const float* __restrict__ l1b,
                                                   const float* __restrict__ l2w, const float* __restrict__ l2b,
                                                   float* __restrict__ out) {
    __shared__ float pooled[H];
    __shared__ float t3[H];
    __shared__ float mid[H / 2];
    int g = blockIdx.x, t = threadIdx.x;
    float c = (float)max(gcnt[g], 1);
    pooled[t] = sums[g * H + t] / c;
    __syncthreads();
    float a = b3[t];
    for (int k = 0; k < H; ++k) a += pooled[k] * w3[k * H + t];
    t3[t] = a;
    __syncthreads();
    if (t < H / 2) {
        float m = l1b[t];
        for (int k = 0; k < H; ++k) m += t3[k] * l1w[k * (H / 2) + t];
        mid[t] = m;
    }
    __syncthreads();
    if (t < 3) {
        float o = l2b[t];
        for (int k = 0; k < H / 2; ++k) o += mid[k] * l2w[k * 3 + t];
        out[g * 3 + t] = o;
    }
}

extern "C" void kernel_launch(void* const* d_in, const int* in_sizes, int n_in,
                              void* d_out, int out_size, void* d_ws, size_t ws_size,
                              hipStream_t stream) {
    const float* x   = (const float*)d_in[0];
    const int*   ei  = (const int*)d_in[2];
    const int*   bat = (const int*)d_in[3];
    const float* w1  = (const float*)d_in[4];
    const float* b1  = (const float*)d_in[5];
    const float* w2  = (const float*)d_in[6];
    const float* b2  = (const float*)d_in[7];
    const float* w3  = (const float*)d_in[8];
    const float* b3  = (const float*)d_in[9];
    const float* l1w = (const float*)d_in[10];
    const float* l1b = (const float*)d_in[11];
    const float* l2w = (const float*)d_in[12];
    const float* l2b = (const float*)d_in[13];
    float* out = (float*)d_out;

    const int N = in_sizes[0] / 128;   // 50000
    const int E = in_sizes[2] / 2;     // 800000
    const int NB = (N + 255) / 256;

    char* ws = (char*)d_ws;
    size_t off = 0;
    auto alloc = [&](size_t bytes) {
        void* p = ws + off;
        off = (off + bytes + 255) & ~(size_t)255;
        return p;
    };
    ushort* yb     = (ushort*)alloc((size_t)N * H * 2);   // bf16 ping (chunk-major)
    ushort* z16    = (ushort*)alloc((size_t)N * H * 2);   // bf16 pong (chunk-major)
    int*    cnt    = (int*)alloc((size_t)N * 4);
    float*  dinv   = (float*)alloc((size_t)N * 4);
    int*    row_ptr= (int*)alloc((size_t)(N + 1) * 4);
    int*    fill   = (int*)alloc((size_t)N * 4);
    ushort* ssrc   = (ushort*)alloc((size_t)E * 2);       // u16 indices (N < 65536)
    int*    bsum   = (int*)alloc(256 * 4);
    int*    boff   = (int*)alloc(256 * 4);
    ushort* wt1h   = (ushort*)alloc((size_t)128 * 256 * 2);
    ushort* wt1l   = (ushort*)alloc((size_t)128 * 256 * 2);
    ushort* wt2h   = (ushort*)alloc((size_t)256 * 256 * 2);
    ushort* wt2l   = (ushort*)alloc((size_t)256 * 256 * 2);
    float*  sums   = (float*)alloc((size_t)NG * H * 4);
    int*    gcnt   = (int*)alloc((size_t)NG * 4);

    hipMemsetAsync(cnt, 0, (size_t)N * 4, stream);

    hist_kernel<<<(E + 255) / 256, 256, 0, stream>>>(ei + E, cnt, E);
    scanA<<<NB, 256, 0, stream>>>(cnt, bsum, dinv, N);
    scanB<<<1, 256, 0, stream>>>(bsum, boff, row_ptr + N, NB, sums, gcnt);
    scanC<<<NB, 256, 0, stream>>>(cnt, boff, row_ptr, fill, N);
    // fused: wconv + scatter + prescale
    int sp_blocks = (N * 32 + 255) / 256;
    wsp_kernel<<<WCONV_BLOCKS + sp_blocks, 256, 0, stream>>>(
        w1, wt1h, wt1l, w2, wt2h, wt2l,
        ei, ei + E, fill, ssrc, E, x, dinv, yb, N);

    const int AGG_BLOCKS = (N + 31) / 32;   // 32 nodes per block (4 waves x 8)
    // layer 1: chunked agg (4 chunks, width 128) -> MFMA GEMM 128->256
    agg_kernel<4><<<AGG_BLOCKS * 4, 256, 0, stream>>>(yb, dinv, row_ptr, ssrc, z16, N);
    mfma_gemm<true><<<dim3((N + 127) / 128, 4), 256, 0, stream>>>(z16, wt1h, wt1l, b1, dinv, yb, N, 128);

    // layer 2: chunked agg (8 chunks, width 256)
    agg_kernel<8><<<AGG_BLOCKS * 8, 256, 0, stream>>>(yb, dinv, row_ptr, ssrc, z16, N);
    mfma_gemm<true><<<dim3((N + 127) / 128, 4), 256, 0, stream>>>(z16, wt2h, wt2l, b2, dinv, yb, N, 256);

    // layer 3: agg only (W3 folded into head)
    agg_kernel<8><<<AGG_BLOCKS * 8, 256, 0, stream>>>(yb, dinv, row_ptr, ssrc, z16, N);

    pool_kernel<<<(N + 127) / 128, 256, 0, stream>>>(z16, bat, sums, gcnt, N);
    head_kernel<<<NG, 256, 0, stream>>>(sums, gcnt, w3, b3, l1w, l1b, l2w, l2b, out);
}